// Round 1
// baseline (10509.376 us; speedup 1.0000x reference)
//
#include <hip/hip_runtime.h>
#include <stdint.h>

// LSTM persistent-scan kernel for MI355X.
// B=64, S=1024, I=H=256. 64 WGs = 4 b-groups x 16 j-slices.
// Each WG: wave w computes gate w for its 16b x 16j tile via mfma 16x16x32 bf16.
// Weights live in registers (bf16 B-frags); h broadcast via device-scope
// flags + threadfence between the 16 WGs of a b-group; c stays in registers.

typedef __attribute__((ext_vector_type(8))) short short8;
typedef __attribute__((ext_vector_type(4))) float f32x4;

#define S_LEN 1024
#define HID 256
#define NB 64
#define PITCH 264  // LDS row pitch in shorts (256 + 8 pad -> 2-way-free banks)

__device__ __forceinline__ short f2bf(float f) {
  union { float f; unsigned u; } v; v.f = f;
  unsigned r = v.u + 0x7FFFu + ((v.u >> 16) & 1u);  // round-nearest-even
  return (short)(r >> 16);
}

__global__ void lstm_zero_flags(unsigned* flags) {
  // 64 flag slots, 32 uints (128 B) apart = 2048 uints
  for (int i = threadIdx.x; i < 2048; i += blockDim.x) flags[i] = 0;
}

__global__ __launch_bounds__(256) void lstm_persist(
    const float* __restrict__ inputs, const float* __restrict__ h0,
    const float* __restrict__ c0,
    const float* __restrict__ w_ii, const float* __restrict__ w_if,
    const float* __restrict__ w_ig, const float* __restrict__ w_io,
    const float* __restrict__ b_ii, const float* __restrict__ b_if,
    const float* __restrict__ b_ig, const float* __restrict__ b_io,
    const float* __restrict__ w_hi, const float* __restrict__ w_hf,
    const float* __restrict__ w_hg, const float* __restrict__ w_ho,
    const float* __restrict__ b_hi, const float* __restrict__ b_hf,
    const float* __restrict__ b_hg, const float* __restrict__ b_ho,
    float* __restrict__ out, unsigned* __restrict__ flags,
    short* __restrict__ hbuf) {
  __shared__ short h_lds[16 * PITCH];
  __shared__ short x_lds[16 * PITCH];
  __shared__ float gates_lds[4][16][16];

  const int tid = threadIdx.x;
  const int wave = tid >> 6;
  const int lane = tid & 63;
  const int bid = blockIdx.x;
  const int gb = bid & 3;    // b-group: rows gb*16..+16
  const int gj = bid >> 2;   // j-slice: cols gj*16..+16

  // staging / elementwise coordinates: thread owns (b_local=row, j_local=col)
  const int row = tid >> 4;
  const int col = tid & 15;
  const int bglob = gb * 16 + row;
  const int jglob = gj * 16 + col;

  // MFMA lane coords
  const int jl = lane & 15;   // A-row (b) for A-frag, B-col (j) for B-frag, D-col
  const int kg = lane >> 4;   // k-group
  const int jw = gj * 16 + jl;

  const float* Wh = (wave == 0) ? w_hi : (wave == 1) ? w_hf : (wave == 2) ? w_hg : w_ho;
  const float* Wi = (wave == 0) ? w_ii : (wave == 1) ? w_if : (wave == 2) ? w_ig : w_io;
  const float* Bi = (wave == 0) ? b_ii : (wave == 1) ? b_if : (wave == 2) ? b_ig : b_io;
  const float* Bh = (wave == 0) ? b_hi : (wave == 1) ? b_hf : (wave == 2) ? b_hg : b_ho;

  // ---- register-stationary weight B-fragments (bf16), loaded once ----
  // B-frag layout (16x16x32): lane holds B[k = kg*8+e][n = jl]; W is [j][k] row-major,
  // so each lane reads 8 consecutive k's of row jw.
  short8 whf[8], wif[8];
#pragma unroll
  for (int kk = 0; kk < 8; ++kk) {
    const float* p = Wh + (size_t)jw * HID + kk * 32 + kg * 8;
    const float* q = Wi + (size_t)jw * HID + kk * 32 + kg * 8;
    short8 s;
#pragma unroll
    for (int e = 0; e < 8; ++e) s[e] = f2bf(p[e]);
    whf[kk] = s;
#pragma unroll
    for (int e = 0; e < 8; ++e) s[e] = f2bf(q[e]);
    wif[kk] = s;
  }
  const float bias = Bi[jw] + Bh[jw];  // both bias terms folded into preactivation

  float c = c0[(size_t)bglob * HID + jglob];

  // ---- prologue: stage x_0 (fp32 -> bf16) and compute xacc for t=0 ----
  {
    const float4* src = (const float4*)(inputs + ((size_t)bglob * S_LEN + 0) * HID);
#pragma unroll
    for (int ch = 0; ch < 4; ++ch) {
      float4 v = src[col + ch * 16];
      union { short s[4]; unsigned long long u; } pk;
      pk.s[0] = f2bf(v.x); pk.s[1] = f2bf(v.y); pk.s[2] = f2bf(v.z); pk.s[3] = f2bf(v.w);
      *(unsigned long long*)&x_lds[row * PITCH + (col + ch * 16) * 4] = pk.u;
    }
  }
  __syncthreads();
  f32x4 xacc = {bias, bias, bias, bias};
#pragma unroll
  for (int kk = 0; kk < 8; ++kk) {
    short8 a = *(const short8*)&x_lds[jl * PITCH + kk * 32 + kg * 8];
    xacc = __builtin_amdgcn_mfma_f32_16x16x32_bf16(a, wif[kk], xacc, 0, 0, 0);
  }

  for (int t = 0; t < S_LEN; ++t) {
    // ---- wait for h_t, then stage it into LDS ----
    if (t > 0) {
      if (tid < 16) {
        const unsigned tgt = (unsigned)t;
        while (__hip_atomic_load(&flags[(gb * 16 + tid) * 32], __ATOMIC_RELAXED,
                                 __HIP_MEMORY_SCOPE_AGENT) < tgt) {}
      }
      __syncthreads();
      __threadfence();  // acquire: invalidate stale cached hbuf lines (cross-XCD)
      const short* src = hbuf + ((size_t)((t & 1) * 4 + gb)) * (16 * HID) + row * HID + col * 16;
      uint4 a0 = *(const uint4*)(src);
      uint4 a1 = *(const uint4*)(src + 8);
      *(uint4*)&h_lds[row * PITCH + col * 16] = a0;
      *(uint4*)&h_lds[row * PITCH + col * 16 + 8] = a1;
    } else {
      const float4* src = (const float4*)(h0 + (size_t)bglob * HID);
#pragma unroll
      for (int ch = 0; ch < 4; ++ch) {
        float4 v = src[col + ch * 16];
        union { short s[4]; unsigned long long u; } pk;
        pk.s[0] = f2bf(v.x); pk.s[1] = f2bf(v.y); pk.s[2] = f2bf(v.z); pk.s[3] = f2bf(v.w);
        *(unsigned long long*)&h_lds[row * PITCH + (col + ch * 16) * 4] = pk.u;
      }
    }
    __syncthreads();  // h_lds ready

    // ---- recurrent GEMM: acc = x-projection (pipelined) + h @ Wh^T ----
    f32x4 acc = xacc;
#pragma unroll
    for (int kk = 0; kk < 8; ++kk) {
      short8 a = *(const short8*)&h_lds[jl * PITCH + kk * 32 + kg * 8];
      acc = __builtin_amdgcn_mfma_f32_16x16x32_bf16(a, whf[kk], acc, 0, 0, 0);
    }

    // activation; D layout: col=jl, row=kg*4+r
#pragma unroll
    for (int r = 0; r < 4; ++r) {
      float v = acc[r];
      float gv = (wave == 2) ? tanhf(v) : (1.0f / (1.0f + __expf(-v)));
      gates_lds[wave][kg * 4 + r][jl] = gv;
    }
    __syncthreads();  // gates ready

    // ---- elementwise state update; thread owns (row, col) ----
    const float iv = gates_lds[0][row][col];
    const float fv = gates_lds[1][row][col];
    const float gg = gates_lds[2][row][col];
    const float ov = gates_lds[3][row][col];
    c = fv * c + iv * gg;
    const float h = ov * tanhf(c);
    out[((size_t)bglob * S_LEN + t) * HID + jglob] = h;
    hbuf[((size_t)(((t + 1) & 1) * 4 + gb)) * (16 * HID) + row * HID + jglob] = f2bf(h);
    if (t == S_LEN - 1) {
      out[(size_t)NB * S_LEN * HID + (size_t)bglob * HID + jglob] = h;              // hN
      out[(size_t)NB * S_LEN * HID + NB * HID + (size_t)bglob * HID + jglob] = c;   // cN
    }

    __threadfence();   // release: h stores visible device-wide
    __syncthreads();
    if (tid == 0) {
      __hip_atomic_store(&flags[(gb * 16 + gj) * 32], (unsigned)(t + 1),
                         __ATOMIC_RELAXED, __HIP_MEMORY_SCOPE_AGENT);
    }

    // ---- pipeline: stage x_{t+1} and compute its projection while peers catch up ----
    if (t < S_LEN - 1) {
      const float4* src = (const float4*)(inputs + ((size_t)bglob * S_LEN + (t + 1)) * HID);
#pragma unroll
      for (int ch = 0; ch < 4; ++ch) {
        float4 v = src[col + ch * 16];
        union { short s[4]; unsigned long long u; } pk;
        pk.s[0] = f2bf(v.x); pk.s[1] = f2bf(v.y); pk.s[2] = f2bf(v.z); pk.s[3] = f2bf(v.w);
        *(unsigned long long*)&x_lds[row * PITCH + (col + ch * 16) * 4] = pk.u;
      }
      __syncthreads();  // x_lds ready
      xacc = (f32x4){bias, bias, bias, bias};
#pragma unroll
      for (int kk = 0; kk < 8; ++kk) {
        short8 a = *(const short8*)&x_lds[jl * PITCH + kk * 32 + kg * 8];
        xacc = __builtin_amdgcn_mfma_f32_16x16x32_bf16(a, wif[kk], xacc, 0, 0, 0);
      }
    }
  }
}

extern "C" void kernel_launch(void* const* d_in, const int* in_sizes, int n_in,
                              void* d_out, int out_size, void* d_ws, size_t ws_size,
                              hipStream_t stream) {
  const float* inputs = (const float*)d_in[0];
  const float* h0 = (const float*)d_in[1];
  const float* c0 = (const float*)d_in[2];
  const float* w_ii = (const float*)d_in[3];
  const float* w_if = (const float*)d_in[4];
  const float* w_ig = (const float*)d_in[5];
  const float* w_io = (const float*)d_in[6];
  const float* b_ii = (const float*)d_in[7];
  const float* b_if = (const float*)d_in[8];
  const float* b_ig = (const float*)d_in[9];
  const float* b_io = (const float*)d_in[10];
  const float* w_hi = (const float*)d_in[11];
  const float* w_hf = (const float*)d_in[12];
  const float* w_hg = (const float*)d_in[13];
  const float* w_ho = (const float*)d_in[14];
  const float* b_hi = (const float*)d_in[15];
  const float* b_hf = (const float*)d_in[16];
  const float* b_hg = (const float*)d_in[17];
  const float* b_ho = (const float*)d_in[18];

  float* out = (float*)d_out;
  unsigned* flags = (unsigned*)d_ws;                 // 8 KB: 64 slots x 128 B
  short* hbuf = (short*)((char*)d_ws + 8192);        // 64 KB: 2 x 4 x 16 x 256 bf16

  lstm_zero_flags<<<1, 256, 0, stream>>>(flags);
  lstm_persist<<<64, 256, 0, stream>>>(
      inputs, h0, c0, w_ii, w_if, w_ig, w_io, b_ii, b_if, b_ig, b_io,
      w_hi, w_hf, w_hg, w_ho, b_hi, b_hf, b_hg, b_ho, out, flags, hbuf);
}

// Round 2
// 3617.502 us; speedup vs baseline: 2.9051x; 2.9051x over previous
//
#include <hip/hip_runtime.h>
#include <stdint.h>

// LSTM persistent-scan kernel for MI355X.
// B=64, S=1024, I=H=256. 64 WGs = 4 b-groups x 16 j-slices.
// Each WG: wave w computes gate w for its 16b x 16j tile via mfma 16x16x32 bf16.
// Weights register-stationary (bf16 B-frags). Cross-WG h exchange uses
// per-access relaxed AGENT-scope atomics (cache-bypass, performed at the
// memory-side coherence point) -- NO cache-wide fences (threadfence on
// multi-XCD lowers to buffer_wbl2/buffer_inv, which was the round-1 10us/step).

typedef __attribute__((ext_vector_type(8))) short short8;
typedef __attribute__((ext_vector_type(4))) float f32x4;

#define S_LEN 1024
#define HID 256
#define NB 64
#define PITCH 264  // LDS row pitch in shorts (256 + 8 pad)

__device__ __forceinline__ short f2bf(float f) {
  union { float f; unsigned u; } v; v.f = f;
  unsigned r = v.u + 0x7FFFu + ((v.u >> 16) & 1u);  // round-nearest-even
  return (short)(r >> 16);
}

__global__ void lstm_zero_flags(unsigned* flags) {
  for (int i = threadIdx.x; i < 2048; i += blockDim.x) flags[i] = 0;
}

__global__ __launch_bounds__(256) void lstm_persist(
    const float* __restrict__ inputs, const float* __restrict__ h0,
    const float* __restrict__ c0,
    const float* __restrict__ w_ii, const float* __restrict__ w_if,
    const float* __restrict__ w_ig, const float* __restrict__ w_io,
    const float* __restrict__ b_ii, const float* __restrict__ b_if,
    const float* __restrict__ b_ig, const float* __restrict__ b_io,
    const float* __restrict__ w_hi, const float* __restrict__ w_hf,
    const float* __restrict__ w_hg, const float* __restrict__ w_ho,
    const float* __restrict__ b_hi, const float* __restrict__ b_hf,
    const float* __restrict__ b_hg, const float* __restrict__ b_ho,
    float* __restrict__ out, unsigned* __restrict__ flags,
    unsigned short* __restrict__ hbuf) {
  __shared__ short h_lds[16 * PITCH];
  __shared__ short x_lds[16 * PITCH];
  __shared__ float gates_lds[4][16][16];

  const int tid = threadIdx.x;
  const int wave = tid >> 6;
  const int lane = tid & 63;
  const int bid = blockIdx.x;
  const int gb = bid & 3;    // b-group: rows gb*16..+16
  const int gj = bid >> 2;   // j-slice: cols gj*16..+16

  const int row = tid >> 4;  // staging/elementwise: thread owns (row=b, col=j)
  const int col = tid & 15;
  const int bglob = gb * 16 + row;
  const int jglob = gj * 16 + col;

  // MFMA lane coords
  const int jl = lane & 15;
  const int kg = lane >> 4;
  const int jw = gj * 16 + jl;

  const float* Wh = (wave == 0) ? w_hi : (wave == 1) ? w_hf : (wave == 2) ? w_hg : w_ho;
  const float* Wi = (wave == 0) ? w_ii : (wave == 1) ? w_if : (wave == 2) ? w_ig : w_io;
  const float* Bi = (wave == 0) ? b_ii : (wave == 1) ? b_if : (wave == 2) ? b_ig : b_io;
  const float* Bh = (wave == 0) ? b_hi : (wave == 1) ? b_hf : (wave == 2) ? b_hg : b_ho;

  // ---- register-stationary weight B-fragments (bf16), loaded once ----
  short8 whf[8], wif[8];
#pragma unroll
  for (int kk = 0; kk < 8; ++kk) {
    const float* p = Wh + (size_t)jw * HID + kk * 32 + kg * 8;
    const float* q = Wi + (size_t)jw * HID + kk * 32 + kg * 8;
    short8 s;
#pragma unroll
    for (int e = 0; e < 8; ++e) s[e] = f2bf(p[e]);
    whf[kk] = s;
#pragma unroll
    for (int e = 0; e < 8; ++e) s[e] = f2bf(q[e]);
    wif[kk] = s;
  }
  const float bias = Bi[jw] + Bh[jw];

  float c = c0[(size_t)bglob * HID + jglob];

  // flags layout: group gb owns flags[gb*64 .. gb*64+15] (one 64B line/group)
  unsigned* gflags = flags + gb * 64;

  // ---- prologue: stage x_0 and compute xacc for t=0 ----
  {
    const float4* src = (const float4*)(inputs + ((size_t)bglob * S_LEN + 0) * HID);
#pragma unroll
    for (int ch = 0; ch < 4; ++ch) {
      float4 v = src[col + ch * 16];
      union { short s[4]; unsigned long long u; } pk;
      pk.s[0] = f2bf(v.x); pk.s[1] = f2bf(v.y); pk.s[2] = f2bf(v.z); pk.s[3] = f2bf(v.w);
      *(unsigned long long*)&x_lds[row * PITCH + (col + ch * 16) * 4] = pk.u;
    }
  }
  __syncthreads();
  f32x4 xacc = {bias, bias, bias, bias};
#pragma unroll
  for (int kk = 0; kk < 8; ++kk) {
    short8 a = *(const short8*)&x_lds[jl * PITCH + kk * 32 + kg * 8];
    xacc = __builtin_amdgcn_mfma_f32_16x16x32_bf16(a, wif[kk], xacc, 0, 0, 0);
  }

  for (int t = 0; t < S_LEN; ++t) {
    // ---- wait for h_t, stage into LDS ----
    if (t > 0) {
      if (tid < 16) {
        const unsigned tgt = (unsigned)t;
        unsigned v = __hip_atomic_load(&gflags[tid], __ATOMIC_RELAXED,
                                       __HIP_MEMORY_SCOPE_AGENT);
        while (v < tgt) {
          __builtin_amdgcn_s_sleep(1);
          v = __hip_atomic_load(&gflags[tid], __ATOMIC_RELAXED,
                                __HIP_MEMORY_SCOPE_AGENT);
        }
      }
      __syncthreads();
      // fresh-by-construction agent-scope loads (no cache invalidate needed)
      const unsigned* src =
          (const unsigned*)(hbuf + ((size_t)((t & 1) * 4 + gb)) * (16 * HID) + row * HID) +
          col * 8;
      unsigned v[8];
#pragma unroll
      for (int e = 0; e < 8; ++e)
        v[e] = __hip_atomic_load(&src[e], __ATOMIC_RELAXED, __HIP_MEMORY_SCOPE_AGENT);
#pragma unroll
      for (int e = 0; e < 8; ++e)
        *(unsigned*)&h_lds[row * PITCH + col * 16 + 2 * e] = v[e];
    } else {
      const float4* src = (const float4*)(h0 + (size_t)bglob * HID);
#pragma unroll
      for (int ch = 0; ch < 4; ++ch) {
        float4 v = src[col + ch * 16];
        union { short s[4]; unsigned long long u; } pk;
        pk.s[0] = f2bf(v.x); pk.s[1] = f2bf(v.y); pk.s[2] = f2bf(v.z); pk.s[3] = f2bf(v.w);
        *(unsigned long long*)&h_lds[row * PITCH + (col + ch * 16) * 4] = pk.u;
      }
    }
    __syncthreads();  // h_lds ready

    // ---- recurrent GEMM ----
    f32x4 acc = xacc;
#pragma unroll
    for (int kk = 0; kk < 8; ++kk) {
      short8 a = *(const short8*)&h_lds[jl * PITCH + kk * 32 + kg * 8];
      acc = __builtin_amdgcn_mfma_f32_16x16x32_bf16(a, whf[kk], acc, 0, 0, 0);
    }

    // activation; D layout: col=jl, row=kg*4+r
#pragma unroll
    for (int r = 0; r < 4; ++r) {
      float v = acc[r];
      float gv = (wave == 2) ? tanhf(v) : (1.0f / (1.0f + __expf(-v)));
      gates_lds[wave][kg * 4 + r][jl] = gv;
    }
    __syncthreads();  // gates ready

    // ---- elementwise state update ----
    const float iv = gates_lds[0][row][col];
    const float fv = gates_lds[1][row][col];
    const float gg = gates_lds[2][row][col];
    const float ov = gates_lds[3][row][col];
    c = fv * c + iv * gg;
    const float h = ov * tanhf(c);

    // ---- critical path first: publish h, drain, signal ----
    __hip_atomic_store(
        &hbuf[((size_t)(((t + 1) & 1) * 4 + gb)) * (16 * HID) + row * HID + jglob],
        (unsigned short)f2bf(h), __ATOMIC_RELAXED, __HIP_MEMORY_SCOPE_AGENT);
    __builtin_amdgcn_s_waitcnt(0);  // per-wave: h stores at coherence point
    __syncthreads();                // all waves drained
    if (tid == 0) {
      __hip_atomic_store(&gflags[gj], (unsigned)(t + 1), __ATOMIC_RELAXED,
                         __HIP_MEMORY_SCOPE_AGENT);
    }

    // ---- off critical path: outputs ----
    out[((size_t)bglob * S_LEN + t) * HID + jglob] = h;
    if (t == S_LEN - 1) {
      out[(size_t)NB * S_LEN * HID + (size_t)bglob * HID + jglob] = h;              // hN
      out[(size_t)NB * S_LEN * HID + NB * HID + (size_t)bglob * HID + jglob] = c;   // cN
    }

    // ---- pipeline: stage x_{t+1}, compute its projection while peers run ----
    if (t < S_LEN - 1) {
      const float4* src = (const float4*)(inputs + ((size_t)bglob * S_LEN + (t + 1)) * HID);
#pragma unroll
      for (int ch = 0; ch < 4; ++ch) {
        float4 v = src[col + ch * 16];
        union { short s[4]; unsigned long long u; } pk;
        pk.s[0] = f2bf(v.x); pk.s[1] = f2bf(v.y); pk.s[2] = f2bf(v.z); pk.s[3] = f2bf(v.w);
        *(unsigned long long*)&x_lds[row * PITCH + (col + ch * 16) * 4] = pk.u;
      }
      __syncthreads();  // x_lds ready
      xacc = (f32x4){bias, bias, bias, bias};
#pragma unroll
      for (int kk = 0; kk < 8; ++kk) {
        short8 a = *(const short8*)&x_lds[jl * PITCH + kk * 32 + kg * 8];
        xacc = __builtin_amdgcn_mfma_f32_16x16x32_bf16(a, wif[kk], xacc, 0, 0, 0);
      }
    }
  }
}

extern "C" void kernel_launch(void* const* d_in, const int* in_sizes, int n_in,
                              void* d_out, int out_size, void* d_ws, size_t ws_size,
                              hipStream_t stream) {
  const float* inputs = (const float*)d_in[0];
  const float* h0 = (const float*)d_in[1];
  const float* c0 = (const float*)d_in[2];
  const float* w_ii = (const float*)d_in[3];
  const float* w_if = (const float*)d_in[4];
  const float* w_ig = (const float*)d_in[5];
  const float* w_io = (const float*)d_in[6];
  const float* b_ii = (const float*)d_in[7];
  const float* b_if = (const float*)d_in[8];
  const float* b_ig = (const float*)d_in[9];
  const float* b_io = (const float*)d_in[10];
  const float* w_hi = (const float*)d_in[11];
  const float* w_hf = (const float*)d_in[12];
  const float* w_hg = (const float*)d_in[13];
  const float* w_ho = (const float*)d_in[14];
  const float* b_hi = (const float*)d_in[15];
  const float* b_hf = (const float*)d_in[16];
  const float* b_hg = (const float*)d_in[17];
  const float* b_ho = (const float*)d_in[18];

  float* out = (float*)d_out;
  unsigned* flags = (unsigned*)d_ws;                         // 8 KB
  unsigned short* hbuf = (unsigned short*)((char*)d_ws + 8192);  // 64 KB

  lstm_zero_flags<<<1, 256, 0, stream>>>(flags);
  lstm_persist<<<64, 256, 0, stream>>>(
      inputs, h0, c0, w_ii, w_if, w_ig, w_io, b_ii, b_if, b_ig, b_io,
      w_hi, w_hf, w_hg, w_ho, b_hi, b_hf, b_hg, b_ho, out, flags, hbuf);
}